// Round 3
// baseline (290.933 us; speedup 1.0000x reference)
//
#include <hip/hip_runtime.h>
#include <hip/hip_fp16.h>

// out = h@Wd1 + (softmax(h@M@e^T)@e)@W2,  M=Wq@Wk^T, W2=Wv@Wd2 (folded on device).
// Round-3: NB=16 (32 rows), LDS 64KB -> 2 blocks/CU (8 waves/SIMD, 100% occ target),
// acc[2][2]/wave, B-operands global-direct, enc rows held as f16 (dot2 logits),
// setprio around MFMA (cross-block role split), ev loads hidden under T-write.

#define B_TOT   16384
#define TQn     2
#define TKn     5
#define NB      16
#define ROWS    32
#define THREADS 1024

typedef _Float16 f16;
typedef _Float16 f16x8 __attribute__((ext_vector_type(8)));
typedef _Float16 f16x4 __attribute__((ext_vector_type(4)));
typedef _Float16 f16x2 __attribute__((ext_vector_type(2)));
typedef float    f32x4 __attribute__((ext_vector_type(4)));

#define HPAN 0
#define TPAN 32768
#define LDS_TOTAL 65536

#define MFMA16(a, b, c) __builtin_amdgcn_mfma_f32_16x16x32_f16(a, b, c, 0, 0, 0)

__global__ __launch_bounds__(THREADS, 8) void fused_attn(
    const float* __restrict__ hptr, const float* __restrict__ eptr,
    const f16* __restrict__ Mt, const f16* __restrict__ Wdt,
    float* __restrict__ outp)
{
  extern __shared__ char smem[];
  const int tid  = threadIdx.x;
  const int lane = tid & 63;
  const int w    = tid >> 6;     // wave 0..15
  const int g    = lane >> 4;
  const int l15  = lane & 15;
  const int b0   = blockIdx.x * NB;
  const int n0   = w * 32;       // wave's output-col base
  const int xsw  = (l15 & 7) << 4;

  // ---- stage H: fp32 global -> f16 LDS (swizzled), 32 rows x 512 ----
  #pragma unroll
  for (int i = 0; i < 4; ++i) {
    int c   = tid + THREADS * i;       // 4096 float4 chunks
    int row = c >> 7;
    int k4  = c & 127;
    int tq  = row & 1;
    int b   = b0 + (row >> 1);
    float4 v = *reinterpret_cast<const float4*>(
        hptr + ((size_t)(tq * B_TOT + b) << 9) + (k4 << 2));
    f16x4 p;
    p[0] = (f16)v.x; p[1] = (f16)v.y; p[2] = (f16)v.z; p[3] = (f16)v.w;
    *reinterpret_cast<f16x4*>(smem + HPAN + row * 1024 +
                              ((k4 << 3) ^ ((row & 7) << 4))) = p;
  }

  // GEMM1 B fragments straight from global (L2-resident weights)
  const f16* bpM = Mt + (size_t)(n0 + l15) * 512 + (g << 3);
  f16x8 bc0 = *reinterpret_cast<const f16x8*>(bpM);
  f16x8 bc1 = *reinterpret_cast<const f16x8*>(bpM + 16 * 512);

  __syncthreads();   // H staged

  // ---- GEMM1: T[32x512] = H @ M (wave owns 32 cols) ----
  f32x4 acc[2][2];
  #pragma unroll
  for (int fm = 0; fm < 2; ++fm)
    #pragma unroll
    for (int fn = 0; fn < 2; ++fn)
      acc[fm][fn] = (f32x4){0.f, 0.f, 0.f, 0.f};
  for (int kt = 0; kt < 16; ++kt) {
    f16x8 af0 = *reinterpret_cast<const f16x8*>(
        smem + HPAN + l15 * 1024 + (((kt << 6) + (g << 4)) ^ xsw));
    f16x8 af1 = *reinterpret_cast<const f16x8*>(
        smem + HPAN + (16 + l15) * 1024 + (((kt << 6) + (g << 4)) ^ xsw));
    f16x8 bn0, bn1;
    if (kt < 15) {
      bn0 = *reinterpret_cast<const f16x8*>(bpM + (kt + 1) * 32);
      bn1 = *reinterpret_cast<const f16x8*>(bpM + 16 * 512 + (kt + 1) * 32);
    }
    __builtin_amdgcn_s_setprio(1);
    acc[0][0] = MFMA16(af0, bc0, acc[0][0]);
    acc[0][1] = MFMA16(af0, bc1, acc[0][1]);
    acc[1][0] = MFMA16(af1, bc0, acc[1][0]);
    acc[1][1] = MFMA16(af1, bc1, acc[1][1]);
    __builtin_amdgcn_s_setprio(0);
    if (kt < 15) { bc0 = bn0; bc1 = bn1; }
  }

  // ---- issue enc loads for this wave's batch (latency hidden under T-write+barrier) ----
  const int b = b0 + w;   // one batch per wave
  float4 e0[TKn], e1[TKn];
  #pragma unroll
  for (int j = 0; j < TKn; ++j) {
    const float4* p4 = reinterpret_cast<const float4*>(
        eptr + ((size_t)(j * B_TOT + b) << 9) + (lane << 3));
    e0[j] = p4[0];
    e1[j] = p4[1];
  }

  // ---- T -> LDS f16 (C/D map: row=(lane>>4)*4+reg, col=lane&15) ----
  #pragma unroll
  for (int fm = 0; fm < 2; ++fm)
    #pragma unroll
    for (int fn = 0; fn < 2; ++fn)
      #pragma unroll
      for (int r = 0; r < 4; ++r) {
        int row = (fm << 4) + (g << 2) + r;
        int col = n0 + (fn << 4) + l15;
        *reinterpret_cast<f16*>(smem + TPAN + row * 1024 +
                                ((col << 1) ^ ((row & 7) << 4))) = (f16)acc[fm][fn][r];
      }
  __syncthreads();   // all T visible

  // ---- softmax + u = att@e (one batch per wave) ----
  f16x8 evh[TKn];
  #pragma unroll
  for (int j = 0; j < TKn; ++j) {
    evh[j][0] = (f16)e0[j].x; evh[j][1] = (f16)e0[j].y;
    evh[j][2] = (f16)e0[j].z; evh[j][3] = (f16)e0[j].w;
    evh[j][4] = (f16)e1[j].x; evh[j][5] = (f16)e1[j].y;
    evh[j][6] = (f16)e1[j].z; evh[j][7] = (f16)e1[j].w;
  }
  f16x8 tvh[TQn];
  #pragma unroll
  for (int i = 0; i < TQn; ++i) {
    int row = (w << 1) + i;
    tvh[i] = *reinterpret_cast<const f16x8*>(
        smem + TPAN + row * 1024 + ((lane << 4) ^ ((row & 7) << 4)));
  }
  float s[TQn][TKn];
  #pragma unroll
  for (int i = 0; i < TQn; ++i)
    #pragma unroll
    for (int j = 0; j < TKn; ++j) {
      float acc_s = 0.f;
      #pragma unroll
      for (int p = 0; p < 4; ++p) {
        f16x2 ta = {tvh[i][2 * p], tvh[i][2 * p + 1]};
        f16x2 ea = {evh[j][2 * p], evh[j][2 * p + 1]};
        acc_s = __builtin_amdgcn_fdot2(ta, ea, acc_s, false);
      }
      s[i][j] = acc_s;
    }
  #pragma unroll
  for (int d = 1; d < 64; d <<= 1)
    #pragma unroll
    for (int i = 0; i < TQn; ++i)
      #pragma unroll
      for (int j = 0; j < TKn; ++j)
        s[i][j] += __shfl_xor(s[i][j], d, 64);
  #pragma unroll
  for (int i = 0; i < TQn; ++i) {
    float mx = s[i][0];
    #pragma unroll
    for (int j = 1; j < TKn; ++j) mx = fmaxf(mx, s[i][j]);
    float sum = 0.f;
    #pragma unroll
    for (int j = 0; j < TKn; ++j) { float e = __expf(s[i][j] - mx); s[i][j] = e; sum += e; }
    float rs = 1.0f / sum;
    int row = (w << 1) + i;
    f16x8 uv;
    #pragma unroll
    for (int m = 0; m < 8; ++m) {
      float uacc = 0.f;
      #pragma unroll
      for (int j = 0; j < TKn; ++j) uacc += s[i][j] * (float)evh[j][m];
      uv[m] = (f16)(uacc * rs);
    }
    *reinterpret_cast<f16x8*>(
        smem + TPAN + row * 1024 + ((lane << 4) ^ ((row & 7) << 4))) = uv;
  }

  // GEMM2 B prologue (issue before barrier)
  const f16* bpW = Wdt + (size_t)(n0 + l15) * 1024 + (g << 3);
  bc0 = *reinterpret_cast<const f16x8*>(bpW);
  bc1 = *reinterpret_cast<const f16x8*>(bpW + 16 * 1024);
  __syncthreads();   // all U visible

  // ---- GEMM2: OUT[32x512] = [H|U] @ Wdt (K=1024) ----
  f32x4 acc2[2][2];
  #pragma unroll
  for (int fm = 0; fm < 2; ++fm)
    #pragma unroll
    for (int fn = 0; fn < 2; ++fn)
      acc2[fm][fn] = (f32x4){0.f, 0.f, 0.f, 0.f};
  for (int kt = 0; kt < 32; ++kt) {
    char* ab = smem + ((kt >> 4) << 15);   // HPAN kt<16, TPAN kt>=16
    f16x8 af0 = *reinterpret_cast<const f16x8*>(
        ab + l15 * 1024 + ((((kt & 15) << 6) + (g << 4)) ^ xsw));
    f16x8 af1 = *reinterpret_cast<const f16x8*>(
        ab + (16 + l15) * 1024 + ((((kt & 15) << 6) + (g << 4)) ^ xsw));
    f16x8 bn0, bn1;
    if (kt < 31) {
      bn0 = *reinterpret_cast<const f16x8*>(bpW + (kt + 1) * 32);
      bn1 = *reinterpret_cast<const f16x8*>(bpW + 16 * 1024 + (kt + 1) * 32);
    }
    __builtin_amdgcn_s_setprio(1);
    acc2[0][0] = MFMA16(af0, bc0, acc2[0][0]);
    acc2[0][1] = MFMA16(af0, bc1, acc2[0][1]);
    acc2[1][0] = MFMA16(af1, bc0, acc2[1][0]);
    acc2[1][1] = MFMA16(af1, bc1, acc2[1][1]);
    __builtin_amdgcn_s_setprio(0);
    if (kt < 31) { bc0 = bn0; bc1 = bn1; }
  }

  // ---- epilogue: fp32 store ----
  #pragma unroll
  for (int fm = 0; fm < 2; ++fm)
    #pragma unroll
    for (int fn = 0; fn < 2; ++fn)
      #pragma unroll
      for (int r = 0; r < 4; ++r) {
        int row = (fm << 4) + (g << 2) + r;
        int col = n0 + (fn << 4) + l15;
        int tq  = row & 1;
        int bb  = b0 + (row >> 1);
        outp[((size_t)(tq * B_TOT + bb) << 9) + col] = acc2[fm][fn][r];
      }
}

// ---- prep (one kernel, 3 block-ranges): Mt[n][k]=(WqWk^T)[k][n];
//      Wdt[n][k<512]=Wdown[k][n]; Wdt[n][512+k2]=(Wv@Wd2)[k2][n] ----
__global__ __launch_bounds__(256) void prep_all(
    const float* __restrict__ Wq, const float* __restrict__ Wk,
    const float* __restrict__ Wv, const float* __restrict__ Wdown,
    f16* __restrict__ Mt, f16* __restrict__ Wdt)
{
  __shared__ float sA[32][68];
  __shared__ float sB[32][68];
  const int tid = threadIdx.x;
  const int bx  = blockIdx.x;

  if (bx < 512) {
    const bool mt  = (bx < 256);
    const int  bb  = mt ? bx : bx - 256;
    const int  n0  = (bb & 15) << 5;
    const int  k0  = (bb >> 4) << 5;
    float accv[4] = {0.f, 0.f, 0.f, 0.f};
    for (int e0 = 0; e0 < 512; e0 += 64) {
      if (mt) {
        #pragma unroll
        for (int i = 0; i < 2; ++i) {
          int c = tid + (i << 8);
          int r = c >> 4, e4 = (c & 15) << 2;
          *reinterpret_cast<float4*>(&sA[r][e4]) =
              *reinterpret_cast<const float4*>(Wq + ((k0 + r) << 9) + e0 + e4);
          *reinterpret_cast<float4*>(&sB[r][e4]) =
              *reinterpret_cast<const float4*>(Wk + ((n0 + r) << 9) + e0 + e4);
        }
      } else {
        #pragma unroll
        for (int i = 0; i < 2; ++i) {
          int c = tid + (i << 8);
          int r = c >> 4, e4 = (c & 15) << 2;
          *reinterpret_cast<float4*>(&sA[r][e4]) =
              *reinterpret_cast<const float4*>(Wv + ((k0 + r) << 9) + e0 + e4);
        }
        #pragma unroll
        for (int i = 0; i < 8; ++i) {
          int c = tid + (i << 8);
          int el = c >> 5, nl = c & 31;
          sB[nl][el] = Wdown[((512 + e0 + el) << 9) + n0 + nl];
        }
      }
      __syncthreads();
      #pragma unroll
      for (int i = 0; i < 4; ++i) {
        int o = tid + (i << 8);
        int nl = o >> 5, kl = o & 31;
        float sacc = accv[i];
        #pragma unroll
        for (int e = 0; e < 64; e += 4) {
          float4 a  = *reinterpret_cast<const float4*>(&sA[kl][e]);
          float4 bq = *reinterpret_cast<const float4*>(&sB[nl][e]);
          sacc += a.x * bq.x + a.y * bq.y + a.z * bq.z + a.w * bq.w;
        }
        accv[i] = sacc;
      }
      __syncthreads();
    }
    #pragma unroll
    for (int i = 0; i < 4; ++i) {
      int o = tid + (i << 8);
      int nl = o >> 5, kl = o & 31;
      if (mt) Mt[((n0 + nl) << 9) + k0 + kl] = (f16)accv[i];
      else    Wdt[((n0 + nl) << 10) + 512 + k0 + kl] = (f16)accv[i];
    }
  } else {
    const int bb = bx - 512;
    const int n0 = (bb & 15) << 5;
    const int k0 = (bb >> 4) << 5;
    #pragma unroll
    for (int i = 0; i < 4; ++i) {
      int c = tid + (i << 8);
      int r = c >> 5, nl = c & 31;
      sA[r][nl] = Wdown[((k0 + r) << 9) + n0 + nl];
    }
    __syncthreads();
    #pragma unroll
    for (int i = 0; i < 4; ++i) {
      int c = tid + (i << 8);
      int nl = c >> 5, kl = c & 31;
      Wdt[((n0 + nl) << 10) + k0 + kl] = (f16)sA[kl][nl];
    }
  }
}

extern "C" void kernel_launch(void* const* d_in, const int* in_sizes, int n_in,
                              void* d_out, int out_size, void* d_ws, size_t ws_size,
                              hipStream_t stream) {
  const float* h   = (const float*)d_in[0];
  const float* enc = (const float*)d_in[1];
  const float* Wq  = (const float*)d_in[2];
  const float* Wk  = (const float*)d_in[3];
  const float* Wv  = (const float*)d_in[4];
  const float* Wd  = (const float*)d_in[5];
  float* out = (float*)d_out;

  f16* Mt  = (f16*)d_ws;            // 512x512 f16
  f16* Wdt = Mt + 512 * 512;        // 512x1024 f16

  (void)hipFuncSetAttribute(reinterpret_cast<const void*>(fused_attn),
                            hipFuncAttributeMaxDynamicSharedMemorySize, LDS_TOTAL);

  prep_all<<<768, 256, 0, stream>>>(Wq, Wk, Wv, Wd, Mt, Wdt);
  fused_attn<<<B_TOT / NB, THREADS, LDS_TOTAL, stream>>>(h, enc, Mt, Wdt, out);
}

// Round 4
// 194.633 us; speedup vs baseline: 1.4948x; 1.4948x over previous
//
#include <hip/hip_runtime.h>
#include <hip/hip_fp16.h>

// out = h@Wd1 + (softmax(h@M@e^T)@e)@W2,  M=Wq@Wk^T, W2=Wv@Wd2 (folded on device).
// Round-4: merged GEMM1 [T|O1] = H @ [M|Wd1] (N=1024,K=512); GEMM2 = acc_o += U@W2 (K=512).
// B streamed through double-buffered LDS in [512n x 32k] chunks (reg-staged, issue-early/
// write-late), raw s_barrier + lgkmcnt(0) (NO vmcnt drain -> loads stay in flight).
// 1024 thr (16 waves), LDS 128KB, VGPR cap 128 (4 waves/SIMD), NB=32.

#define B_TOT   16384
#define TQn     2
#define TKn     5
#define NB      32
#define ROWS    64
#define THREADS 1024

typedef _Float16 f16;
typedef _Float16 f16x8 __attribute__((ext_vector_type(8)));
typedef _Float16 f16x4 __attribute__((ext_vector_type(4)));
typedef _Float16 f16x2 __attribute__((ext_vector_type(2)));
typedef float    f32x4 __attribute__((ext_vector_type(4)));

#define PAN       0          // 64 rows x 1024B: H, later overwritten by T then U
#define BBASE     65536      // two 32KB B-chunk buffers
#define LDS_TOTAL 131072

#define MFMA16(a,b,c) __builtin_amdgcn_mfma_f32_16x16x32_f16(a, b, c, 0, 0, 0)

// barrier WITHOUT vmcnt drain: ds-writes made visible (lgkmcnt), global loads stay in flight
#define BAR() do { asm volatile("s_waitcnt lgkmcnt(0)" ::: "memory"); \
                   __builtin_amdgcn_s_barrier(); } while (0)

__global__ __launch_bounds__(THREADS, 4) void fused_attn(
    const float* __restrict__ hptr, const float* __restrict__ eptr,
    const f16* __restrict__ Mt2, const f16* __restrict__ W2t,
    float* __restrict__ outp)
{
  extern __shared__ char smem[];
  const int tid  = threadIdx.x;
  const int lane = tid & 63;
  const int w    = tid >> 6;      // wave 0..15
  const int g    = lane >> 4;
  const int l15  = lane & 15;
  const int b0   = blockIdx.x * NB;
  const int n0   = w * 32;        // wave's col base (T and O1 slices share it)
  const int xsw  = (l15 & 7) << 4;              // A-panel read swizzle
  const int bswz = ((g ^ (l15 & 3)) << 4);      // B-chunk read swizzle

  // B-staging identity: thread covers row srow, granules p0,p0+1 (16B each)
  const int srow = tid >> 1;            // 0..511
  const int p0   = (tid & 1) << 1;      // 0 or 2
  const int sq0  = (p0)     ^ (srow & 3);
  const int sq1  = (p0 + 1) ^ (srow & 3);

  // ---- issue H loads (8 x float4/thread) ----
  float4 hv[8];
  #pragma unroll
  for (int i = 0; i < 8; ++i) {
    int c   = tid + THREADS * i;        // 8192 float4 = 64 rows x 128
    int row = c >> 7;
    int k4  = c & 127;
    int tq  = row & 1;
    int b   = b0 + (row >> 1);
    hv[i] = *reinterpret_cast<const float4*>(
        hptr + ((size_t)(tq * B_TOT + b) << 9) + (k4 << 2));
  }
  // ---- issue B chunk s=0 (G1 c=0,h=0) ----
  uint4 rA, rB;
  {
    const f16* sp = Mt2 + (size_t)srow * 512 + p0 * 8;
    rA = *reinterpret_cast<const uint4*>(sp);
    rB = *reinterpret_cast<const uint4*>(sp + 8);
  }
  // ---- H -> LDS f16 (swizzled) ----
  #pragma unroll
  for (int i = 0; i < 8; ++i) {
    int c   = tid + THREADS * i;
    int row = c >> 7;
    int k4  = c & 127;
    f16x4 p;
    p[0] = (f16)hv[i].x; p[1] = (f16)hv[i].y; p[2] = (f16)hv[i].z; p[3] = (f16)hv[i].w;
    *reinterpret_cast<f16x4*>(smem + PAN + row * 1024 +
                              ((k4 << 3) ^ ((row & 7) << 4))) = p;
  }

  // ---- GEMM1: [T|O1] = H @ Mt2, 16 K-chunks x 2 N-halves, 2-phase pipeline ----
  f32x4 acc_t[4][2], acc_o[4][2];
  #pragma unroll
  for (int fm = 0; fm < 4; ++fm)
    #pragma unroll
    for (int fn = 0; fn < 2; ++fn) {
      acc_t[fm][fn] = (f32x4){0.f, 0.f, 0.f, 0.f};
      acc_o[fm][fn] = (f32x4){0.f, 0.f, 0.f, 0.f};
    }
  f16x8 af[4];

  for (int c = 0; c < 16; ++c) {
    // ===== step s=2c (h=0, T-half) =====
    {
      char* bb = smem + BBASE;          // buf parity = s&1 = 0
      *reinterpret_cast<uint4*>(bb + srow * 64 + (sq0 << 4)) = rA;
      *reinterpret_cast<uint4*>(bb + srow * 64 + (sq1 << 4)) = rB;
      // issue s+1 (h=1 of same c)
      const f16* sp = Mt2 + (size_t)(512 + srow) * 512 + c * 32 + p0 * 8;
      rA = *reinterpret_cast<const uint4*>(sp);
      rB = *reinterpret_cast<const uint4*>(sp + 8);
      BAR();
      #pragma unroll
      for (int fm = 0; fm < 4; ++fm)
        af[fm] = *reinterpret_cast<const f16x8*>(
            smem + PAN + (fm * 16 + l15) * 1024 + (((c << 6) + (g << 4)) ^ xsw));
      f16x8 bf0 = *reinterpret_cast<const f16x8*>(bb + (n0 + l15) * 64 + bswz);
      f16x8 bf1 = *reinterpret_cast<const f16x8*>(bb + (n0 + 16 + l15) * 64 + bswz);
      __builtin_amdgcn_s_setprio(1);
      #pragma unroll
      for (int fm = 0; fm < 4; ++fm) {
        acc_t[fm][0] = MFMA16(af[fm], bf0, acc_t[fm][0]);
        acc_t[fm][1] = MFMA16(af[fm], bf1, acc_t[fm][1]);
      }
      __builtin_amdgcn_s_setprio(0);
    }
    // ===== step s=2c+1 (h=1, O1-half) =====
    {
      char* bb = smem + BBASE + 32768;  // buf parity 1
      *reinterpret_cast<uint4*>(bb + srow * 64 + (sq0 << 4)) = rA;
      *reinterpret_cast<uint4*>(bb + srow * 64 + (sq1 << 4)) = rB;
      if (c < 15) {                     // issue s+2 = (c+1,h=0)
        const f16* sp = Mt2 + (size_t)srow * 512 + (c + 1) * 32 + p0 * 8;
        rA = *reinterpret_cast<const uint4*>(sp);
        rB = *reinterpret_cast<const uint4*>(sp + 8);
      }
      BAR();
      f16x8 bf0 = *reinterpret_cast<const f16x8*>(bb + (n0 + l15) * 64 + bswz);
      f16x8 bf1 = *reinterpret_cast<const f16x8*>(bb + (n0 + 16 + l15) * 64 + bswz);
      __builtin_amdgcn_s_setprio(1);
      #pragma unroll
      for (int fm = 0; fm < 4; ++fm) {
        acc_o[fm][0] = MFMA16(af[fm], bf0, acc_o[fm][0]);
        acc_o[fm][1] = MFMA16(af[fm], bf1, acc_o[fm][1]);
      }
      __builtin_amdgcn_s_setprio(0);
    }
  }

  // ---- T -> panel (overwrite H; GEMM2 no longer needs H) ----
  #pragma unroll
  for (int fm = 0; fm < 4; ++fm)
    #pragma unroll
    for (int fn = 0; fn < 2; ++fn)
      #pragma unroll
      for (int r = 0; r < 4; ++r) {
        int row = (fm << 4) + (g << 2) + r;
        int col = n0 + (fn << 4) + l15;
        *reinterpret_cast<f16*>(smem + PAN + row * 1024 +
                                ((col << 1) ^ ((row & 7) << 4))) = (f16)acc_t[fm][fn][r];
      }
  BAR();   // all T visible

  // ---- issue G2 chunk c2=0 loads (latency hidden under softmax) ----
  {
    const f16* sp = W2t + (size_t)srow * 512 + p0 * 8;
    rA = *reinterpret_cast<const uint4*>(sp);
    rB = *reinterpret_cast<const uint4*>(sp + 8);
  }

  // ---- softmax + u = att@e (fp32), 2 batches per wave ----
  #pragma unroll 1
  for (int bi = 0; bi < 2; ++bi) {
    const int bl = (w << 1) + bi;
    const int b  = b0 + bl;
    float4 e0[TKn], e1[TKn];
    #pragma unroll
    for (int j = 0; j < TKn; ++j) {
      const float4* p4 = reinterpret_cast<const float4*>(
          eptr + ((size_t)(j * B_TOT + b) << 9) + (lane << 3));
      e0[j] = p4[0];
      e1[j] = p4[1];
    }
    f16x8 evh[TKn];
    #pragma unroll
    for (int j = 0; j < TKn; ++j) {
      evh[j][0] = (f16)e0[j].x; evh[j][1] = (f16)e0[j].y;
      evh[j][2] = (f16)e0[j].z; evh[j][3] = (f16)e0[j].w;
      evh[j][4] = (f16)e1[j].x; evh[j][5] = (f16)e1[j].y;
      evh[j][6] = (f16)e1[j].z; evh[j][7] = (f16)e1[j].w;
    }
    f16x8 tvh[TQn];
    #pragma unroll
    for (int i = 0; i < TQn; ++i) {
      int row = (bl << 1) + i;
      tvh[i] = *reinterpret_cast<const f16x8*>(
          smem + PAN + row * 1024 + ((lane << 4) ^ ((row & 7) << 4)));
    }
    float s[TQn][TKn];
    #pragma unroll
    for (int i = 0; i < TQn; ++i)
      #pragma unroll
      for (int j = 0; j < TKn; ++j) {
        float a = 0.f;
        #pragma unroll
        for (int p = 0; p < 4; ++p) {
          f16x2 ta = {tvh[i][2 * p], tvh[i][2 * p + 1]};
          f16x2 ea = {evh[j][2 * p], evh[j][2 * p + 1]};
          a = __builtin_amdgcn_fdot2(ta, ea, a, false);
        }
        s[i][j] = a;
      }
    #pragma unroll
    for (int d = 1; d < 64; d <<= 1)
      #pragma unroll
      for (int i = 0; i < TQn; ++i)
        #pragma unroll
        for (int j = 0; j < TKn; ++j)
          s[i][j] += __shfl_xor(s[i][j], d, 64);
    #pragma unroll
    for (int i = 0; i < TQn; ++i) {
      float mx = s[i][0];
      #pragma unroll
      for (int j = 1; j < TKn; ++j) mx = fmaxf(mx, s[i][j]);
      float sum = 0.f;
      #pragma unroll
      for (int j = 0; j < TKn; ++j) { float e = __expf(s[i][j] - mx); s[i][j] = e; sum += e; }
      float rs = 1.0f / sum;
      int row = (bl << 1) + i;
      f16x8 uv;
      #pragma unroll
      for (int m = 0; m < 8; ++m) {
        float ua = 0.f;
        #pragma unroll
        for (int j = 0; j < TKn; ++j) ua += s[i][j] * (float)evh[j][m];
        uv[m] = (f16)(ua * rs);
      }
      *reinterpret_cast<f16x8*>(
          smem + PAN + row * 1024 + ((lane << 4) ^ ((row & 7) << 4))) = uv;
    }
  }
  BAR();   // all U visible

  // ---- GEMM2: acc_o += U @ W2t (K=512, 16 chunks, same 2-phase pipeline) ----
  for (int c2 = 0; c2 < 16; ++c2) {
    char* bb = smem + BBASE + ((c2 & 1) << 15);
    *reinterpret_cast<uint4*>(bb + srow * 64 + (sq0 << 4)) = rA;
    *reinterpret_cast<uint4*>(bb + srow * 64 + (sq1 << 4)) = rB;
    if (c2 < 15) {
      const f16* sp = W2t + (size_t)srow * 512 + (c2 + 1) * 32 + p0 * 8;
      rA = *reinterpret_cast<const uint4*>(sp);
      rB = *reinterpret_cast<const uint4*>(sp + 8);
    }
    BAR();
    f16x8 uf[4];
    #pragma unroll
    for (int fm = 0; fm < 4; ++fm)
      uf[fm] = *reinterpret_cast<const f16x8*>(
          smem + PAN + (fm * 16 + l15) * 1024 + (((c2 << 6) + (g << 4)) ^ xsw));
    f16x8 bf0 = *reinterpret_cast<const f16x8*>(bb + (n0 + l15) * 64 + bswz);
    f16x8 bf1 = *reinterpret_cast<const f16x8*>(bb + (n0 + 16 + l15) * 64 + bswz);
    __builtin_amdgcn_s_setprio(1);
    #pragma unroll
    for (int fm = 0; fm < 4; ++fm) {
      acc_o[fm][0] = MFMA16(uf[fm], bf0, acc_o[fm][0]);
      acc_o[fm][1] = MFMA16(uf[fm], bf1, acc_o[fm][1]);
    }
    __builtin_amdgcn_s_setprio(0);
  }

  // ---- epilogue: fp32 store ----
  #pragma unroll
  for (int fm = 0; fm < 4; ++fm)
    #pragma unroll
    for (int fn = 0; fn < 2; ++fn)
      #pragma unroll
      for (int r = 0; r < 4; ++r) {
        int row = (fm << 4) + (g << 2) + r;
        int col = n0 + (fn << 4) + l15;
        int tq  = row & 1;
        int bb  = b0 + (row >> 1);
        outp[((size_t)(tq * B_TOT + bb) << 9) + col] = acc_o[fm][fn][r];
      }
}

// ---- prep: Mt2[n][k] (n<512: (WqWk^T)^T; n>=512: Wdown[k][n-512]), W2t[n][k]=(Wv@Wd2)^T ----
__global__ __launch_bounds__(256) void prep_all(
    const float* __restrict__ Wq, const float* __restrict__ Wk,
    const float* __restrict__ Wv, const float* __restrict__ Wdown,
    f16* __restrict__ Mt2, f16* __restrict__ W2t)
{
  __shared__ float sA[32][68];
  __shared__ float sB[32][68];
  const int tid = threadIdx.x;
  const int bx  = blockIdx.x;

  if (bx < 512) {
    const bool mt  = (bx < 256);
    const int  bb  = mt ? bx : bx - 256;
    const int  n0  = (bb & 15) << 5;
    const int  k0  = (bb >> 4) << 5;
    float accv[4] = {0.f, 0.f, 0.f, 0.f};
    for (int e0 = 0; e0 < 512; e0 += 64) {
      if (mt) {
        #pragma unroll
        for (int i = 0; i < 2; ++i) {
          int c = tid + (i << 8);
          int r = c >> 4, e4 = (c & 15) << 2;
          *reinterpret_cast<float4*>(&sA[r][e4]) =
              *reinterpret_cast<const float4*>(Wq + ((k0 + r) << 9) + e0 + e4);
          *reinterpret_cast<float4*>(&sB[r][e4]) =
              *reinterpret_cast<const float4*>(Wk + ((n0 + r) << 9) + e0 + e4);
        }
      } else {
        #pragma unroll
        for (int i = 0; i < 2; ++i) {
          int c = tid + (i << 8);
          int r = c >> 4, e4 = (c & 15) << 2;
          *reinterpret_cast<float4*>(&sA[r][e4]) =
              *reinterpret_cast<const float4*>(Wv + ((k0 + r) << 9) + e0 + e4);
        }
        #pragma unroll
        for (int i = 0; i < 8; ++i) {
          int c = tid + (i << 8);
          int el = c >> 5, nl = c & 31;
          sB[nl][el] = Wdown[((512 + e0 + el) << 9) + n0 + nl];
        }
      }
      __syncthreads();
      #pragma unroll
      for (int i = 0; i < 4; ++i) {
        int o = tid + (i << 8);
        int nl = o >> 5, kl = o & 31;
        float sacc = accv[i];
        #pragma unroll
        for (int e = 0; e < 64; e += 4) {
          float4 a  = *reinterpret_cast<const float4*>(&sA[kl][e]);
          float4 bq = *reinterpret_cast<const float4*>(&sB[nl][e]);
          sacc += a.x * bq.x + a.y * bq.y + a.z * bq.z + a.w * bq.w;
        }
        accv[i] = sacc;
      }
      __syncthreads();
    }
    #pragma unroll
    for (int i = 0; i < 4; ++i) {
      int o = tid + (i << 8);
      int nl = o >> 5, kl = o & 31;
      if (mt) Mt2[((n0 + nl) << 9) + k0 + kl] = (f16)accv[i];
      else    W2t[((n0 + nl) << 9) + k0 + kl] = (f16)accv[i];
    }
  } else {
    const int bb = bx - 512;
    const int n0 = (bb & 15) << 5;
    const int k0 = (bb >> 4) << 5;
    #pragma unroll
    for (int i = 0; i < 4; ++i) {
      int c = tid + (i << 8);
      int r = c >> 5, nl = c & 31;
      sA[r][nl] = Wdown[((k0 + r) << 9) + n0 + nl];
    }
    __syncthreads();
    #pragma unroll
    for (int i = 0; i < 4; ++i) {
      int c = tid + (i << 8);
      int nl = c >> 5, kl = c & 31;
      Mt2[((512 + n0 + nl) << 9) + k0 + kl] = (f16)sA[kl][nl];
    }
  }
}

extern "C" void kernel_launch(void* const* d_in, const int* in_sizes, int n_in,
                              void* d_out, int out_size, void* d_ws, size_t ws_size,
                              hipStream_t stream) {
  const float* h   = (const float*)d_in[0];
  const float* enc = (const float*)d_in[1];
  const float* Wq  = (const float*)d_in[2];
  const float* Wk  = (const float*)d_in[3];
  const float* Wv  = (const float*)d_in[4];
  const float* Wd  = (const float*)d_in[5];
  float* out = (float*)d_out;

  f16* Mt2 = (f16*)d_ws;              // 1024 x 512 f16 = 1MB
  f16* W2t = Mt2 + 1024 * 512;        // 512 x 512 f16 = 0.5MB

  (void)hipFuncSetAttribute(reinterpret_cast<const void*>(fused_attn),
                            hipFuncAttributeMaxDynamicSharedMemorySize, LDS_TOTAL);

  prep_all<<<768, 256, 0, stream>>>(Wq, Wk, Wv, Wd, Mt2, W2t);
  fused_attn<<<B_TOT / NB, THREADS, LDS_TOTAL, stream>>>(h, enc, Mt2, W2t, out);
}